// Round 11
// baseline (130.070 us; speedup 1.0000x reference)
//
#include <hip/hip_runtime.h>
#include <math.h>

// Problem constants
constexpr int NH    = 778;           // hand verts per batch
constexpr int GRIDC = 16;            // cells per axis (0.1 m cube -> 6.25 mm cells)
constexpr int NCELL = GRIDC * GRIDC * GRIDC;   // 4096
constexpr int CAP   = 40;            // bucket capacity (Poisson mean ~9.8; P(>40)~1e-14)
constexpr float CELL     = 0.1f / GRIDC;       // 0.00625
constexpr float INV_CELL = GRIDC / 0.1f;       // 160
constexpr int SPLIT = 4;             // lanes cooperating per query point

__device__ __forceinline__ int clampc(int v) {
    return min(GRIDC - 1, max(0, v));
}

// ---------------------------------------------------------------------------
// K1: bin obj points into per-(batch,cell) buckets. Overflow (idx >= CAP)
// goes to a global list tagged with batch (capacity = ALL points -> always
// correct, degrades gracefully if data were adversarial). Insertion order is
// atomic-nondeterministic; min over the union is order-independent.
// ---------------------------------------------------------------------------
__global__ __launch_bounds__(256) void bin_kernel(
    const float* __restrict__ obj,   // [B, V, 3] flat
    int* __restrict__ cnt,           // [B*NCELL]
    int* __restrict__ ocnt,          // overflow counter
    float4* __restrict__ buckets,    // [B*NCELL*CAP]
    float4* __restrict__ ovf,        // [B*V] worst case
    int total, int V)
{
    const int i = blockIdx.x * 256 + threadIdx.x;
    if (i >= total) return;
    const float x = obj[3 * i + 0];
    const float y = obj[3 * i + 1];
    const float z = obj[3 * i + 2];
    const int cx = clampc((int)(x * INV_CELL));
    const int cy = clampc((int)(y * INV_CELL));
    const int cz = clampc((int)(z * INV_CELL));
    const int b = i / V;
    const int cell = b * NCELL + (cz * GRIDC + cy) * GRIDC + cx;
    const int idx = atomicAdd(&cnt[cell], 1);
    if (idx < CAP) {
        buckets[(size_t)cell * CAP + idx] = make_float4(x, y, z, 0.f);
    } else {
        const int oi = atomicAdd(ocnt, 1);   // oi < total always
        ovf[oi] = make_float4(x, y, z, __int_as_float(b));
    }
}

// ---------------------------------------------------------------------------
// K2: exact grid NN query. 4 lanes per hand point (k-strided bucket scan,
// shfl-combined). Exactness: hand point h lies inside its own cell, so any
// point in a cell with Chebyshev distance > r from h's cell is at Euclidean
// distance >= r*CELL; after completing cube radius r we stop iff
// best_d2 <= (r*CELL)^2. Radius 15 covers the whole 16^3 grid. Subtract-form
// d2 (>= 0 by construction). Writes d2 as plain float (no init needed).
// ---------------------------------------------------------------------------
__global__ __launch_bounds__(256) void query_kernel(
    const float* __restrict__ hand,    // [B, NH, 3] flat
    const int* __restrict__ cnt,       // [B*NCELL]
    const float4* __restrict__ buckets,// [B*NCELL*CAP]
    const float4* __restrict__ ovf,
    const int* __restrict__ ocnt,
    float* __restrict__ dist,          // [B*NH] min d2
    int B)
{
    const int gid = blockIdx.x * 256 + threadIdx.x;
    const int i   = gid >> 2;          // hand point id
    const int sub = gid & (SPLIT - 1);
    if (i >= B * NH) return;
    const int b = i / NH;

    const float hx = hand[3 * i + 0];
    const float hy = hand[3 * i + 1];
    const float hz = hand[3 * i + 2];
    const int hcx = clampc((int)(hx * INV_CELL));
    const int hcy = clampc((int)(hy * INV_CELL));
    const int hcz = clampc((int)(hz * INV_CELL));

    const int cbase = b * NCELL;
    float best = 3.4e38f;

    // scan one cell's bucket, k strided by SPLIT across the 4 sub-lanes
    auto scan_cell = [&](int cell) {
        const int n = min(cnt[cbase + cell], CAP);
        const float4* bp = buckets + (size_t)(cbase + cell) * CAP;
        for (int k = sub; k < n; k += SPLIT) {
            const float4 p = bp[k];
            const float dx = p.x - hx, dy = p.y - hy, dz = p.z - hz;
            best = fminf(best, fmaf(dx, dx, fmaf(dy, dy, dz * dz)));
        }
    };

    // radius-1 cube (27 cells; radius-0 alone can never certify termination)
    for (int dz = -1; dz <= 1; ++dz) {
        const int cz = hcz + dz;
        if (cz < 0 || cz >= GRIDC) continue;
        for (int dy = -1; dy <= 1; ++dy) {
            const int cy = hcy + dy;
            if (cy < 0 || cy >= GRIDC) continue;
            for (int dx = -1; dx <= 1; ++dx) {
                const int cx = hcx + dx;
                if (cx < 0 || cx >= GRIDC) continue;
                scan_cell((cz * GRIDC + cy) * GRIDC + cx);
            }
        }
    }
    best = fminf(best, __shfl_xor(best, 1));
    best = fminf(best, __shfl_xor(best, 2));

    // expanding shells until the exactness bound certifies the min
    for (int r = 2; r < GRIDC; ++r) {
        const float bnd = (float)(r - 1) * CELL;
        if (best <= bnd * bnd) break;
        for (int dz = -r; dz <= r; ++dz) {
            const int cz = hcz + dz;
            if (cz < 0 || cz >= GRIDC) continue;
            const int adz = abs(dz);
            for (int dy = -r; dy <= r; ++dy) {
                const int cy = hcy + dy;
                if (cy < 0 || cy >= GRIDC) continue;
                const int ady = abs(dy);
                for (int dx = -r; dx <= r; ++dx) {
                    if (max(max(abs(dx), ady), adz) != r) continue;  // shell only
                    const int cx = hcx + dx;
                    if (cx < 0 || cx >= GRIDC) continue;
                    scan_cell((cz * GRIDC + cy) * GRIDC + cx);
                }
            }
        }
        best = fminf(best, __shfl_xor(best, 1));
        best = fminf(best, __shfl_xor(best, 2));
    }

    // overflow list (normally empty)
    const int on = *ocnt;
    for (int k = sub; k < on; k += SPLIT) {
        const float4 p = ovf[k];
        if (__float_as_int(p.w) == b) {
            const float dx = p.x - hx, dy = p.y - hy, dz = p.z - hz;
            best = fminf(best, fmaf(dx, dx, fmaf(dy, dy, dz * dz)));
        }
    }
    best = fminf(best, __shfl_xor(best, 1));
    best = fminf(best, __shfl_xor(best, 2));

    if (sub == 0) dist[i] = best;
}

// ---------------------------------------------------------------------------
// Fallback brute-force (R10 kernel) if ws is too small for the grid. Writes
// uint bit-pattern mins of d2 — identical representation to plain float d2.
// ---------------------------------------------------------------------------
typedef float v2f __attribute__((ext_vector_type(2)));
constexpr int FT = 16, FG = 4, FBLK = 256, FCHUNK = 2560;
constexpr int FNBX = (NH + FG * FT - 1) / (FG * FT);
constexpr int FLPP = FCHUNK / FBLK, FPP = FLPP / 2;

__global__ __launch_bounds__(FBLK, 2) void nn_brute_kernel(
    const float* __restrict__ hand, const float* __restrict__ obj,
    unsigned int* __restrict__ minb, int V)
{
    __shared__ float s_red[4][16 * 65];
    const int bx = blockIdx.x, c = blockIdx.y, b = blockIdx.z;
    const int tid = threadIdx.x, wave = tid >> 6, lane = tid & 63;
    const int r = lane & 15, seg = lane >> 4;
    const float* ob = obj + (size_t)b * V * 3;
    const int base = c * FCHUNK + tid;
    v2f ox2[FPP], oy2[FPP], oz2[FPP], oq2[FPP];
#pragma unroll
    for (int p = 0; p < FPP; ++p) {
        const int ja = min(base + (2 * p + 0) * FBLK, V - 1);
        const int jb = min(base + (2 * p + 1) * FBLK, V - 1);
        const float xa = ob[3 * ja], ya = ob[3 * ja + 1], za = ob[3 * ja + 2];
        const float xb = ob[3 * jb], yb = ob[3 * jb + 1], zb = ob[3 * jb + 2];
        ox2[p] = (v2f){-2.f * xa, -2.f * xb};
        oy2[p] = (v2f){-2.f * ya, -2.f * yb};
        oz2[p] = (v2f){-2.f * za, -2.f * zb};
        oq2[p] = (v2f){fmaf(xa, xa, fmaf(ya, ya, za * za)),
                       fmaf(xb, xb, fmaf(yb, yb, zb * zb))};
    }
    const float* hb = hand + (size_t)b * NH * 3;
    float* sw = &s_red[wave][0];
#pragma unroll 1
    for (int g = 0; g < FG; ++g) {
        float hx[FT], hy[FT], hz[FT], m[FT];
#pragma unroll
        for (int t = 0; t < FT; ++t) {
            const int h = min((bx * FG + g) * FT + t, NH - 1);
            hx[t] = hb[3 * h]; hy[t] = hb[3 * h + 1]; hz[t] = hb[3 * h + 2];
            m[t] = 3.4e38f;
        }
#pragma unroll
        for (int p = 0; p < FPP; ++p) {
#pragma unroll
            for (int t = 0; t < FT; ++t) {
                v2f a = __builtin_elementwise_fma(ox2[p], (v2f){hx[t], hx[t]}, oq2[p]);
                a = __builtin_elementwise_fma(oy2[p], (v2f){hy[t], hy[t]}, a);
                a = __builtin_elementwise_fma(oz2[p], (v2f){hz[t], hz[t]}, a);
                m[t] = fminf(fminf(a.x, a.y), m[t]);
            }
        }
#pragma unroll
        for (int t = 0; t < FT; ++t) {
            const float hq = fmaf(hx[t], hx[t], fmaf(hy[t], hy[t], hz[t] * hz[t]));
            sw[t * 65 + lane] = m[t] + hq;
        }
        __builtin_amdgcn_wave_barrier();
        float v = 3.4e38f;
        const int rb = r * 65 + seg * 16;
#pragma unroll
        for (int j = 0; j < 16; ++j) v = fminf(v, sw[rb + j]);
        __builtin_amdgcn_wave_barrier();
        v = fminf(v, __shfl_xor(v, 16));
        v = fminf(v, __shfl_xor(v, 32));
        if (seg == 0) {
            const int hidx = (bx * FG + g) * FT + r;
            if (hidx < NH) {
                const unsigned bits = __float_as_uint(fmaxf(v, 0.f));
                unsigned int* p = &minb[b * NH + hidx];
                if (bits < *((volatile unsigned int*)p)) atomicMin(p, bits);
            }
        }
    }
}

// ---------------------------------------------------------------------------
// Final reduction -> 6 scalar outputs (dist buffer holds d2 as plain floats)
// ---------------------------------------------------------------------------
__global__ __launch_bounds__(256) void finalize_kernel(
    const float* __restrict__ dist, float* __restrict__ out, int B)
{
    constexpr float COLL = 0.005f;
    constexpr float CONT = 0.01f;
    const int total = B * NH;
    const int tid = threadIdx.x;

    double sum_d = 0.0, pen_sum = 0.0, att_sum = 0.0;
    int pen_cnt = 0, att_cnt = 0;
    for (int i = tid; i < total; i += 256) {
        const float d = sqrtf(fmaxf(dist[i], 0.f));
        sum_d += (double)d;
        if (d < COLL) { const float t = COLL - d; pen_sum += (double)(t * t); pen_cnt++; }
        const int n = i % NH;
        const bool isc = (n == 745) | (n == 317) | (n == 444) | (n == 556) |
                         (n == 673) | (n == 95)  | (n == 182) | (n == 234) |
                         (n == 279) | (n == 320);
        if (isc & (d > COLL) & (d < CONT)) { att_sum += (double)(d * d); att_cnt++; }
    }

    __shared__ double sd[256], sp[256], sa[256];
    __shared__ int    cp[256], ca[256];
    sd[tid] = sum_d; sp[tid] = pen_sum; sa[tid] = att_sum;
    cp[tid] = pen_cnt; ca[tid] = att_cnt;
    __syncthreads();
    for (int off = 128; off > 0; off >>= 1) {
        if (tid < off) {
            sd[tid] += sd[tid + off]; sp[tid] += sp[tid + off];
            sa[tid] += sa[tid + off];
            cp[tid] += cp[tid + off]; ca[tid] += ca[tid + off];
        }
        __syncthreads();
    }
    if (tid == 0) {
        const double pen_loss = cp[0] > 0 ? sp[0] / (double)cp[0] : 0.0;
        const double att_loss = ca[0] > 0 ? sa[0] / (double)ca[0] : 0.0;
        out[0] = (float)(100.0 * pen_loss + 10.0 * att_loss);
        out[1] = (float)pen_loss;
        out[2] = (float)att_loss;
        out[3] = (float)(sd[0] / (double)total);
        out[4] = (float)ca[0];
        out[5] = (float)cp[0];
    }
}

extern "C" void kernel_launch(void* const* d_in, const int* in_sizes, int n_in,
                              void* d_out, int out_size, void* d_ws, size_t ws_size,
                              hipStream_t stream) {
    const float* hand = (const float*)d_in[0];  // [B, 778, 3] fp32
    const float* obj  = (const float*)d_in[1];  // [B, V, 3]   fp32
    // d_in[2]/d_in[3] (faces): unused by the loss

    const int B = in_sizes[0] / (NH * 3);
    const int V = in_sizes[1] / (B * 3);
    const int total = B * V;

    // workspace layout
    float* dist = (float*)d_ws;                                   // [B*NH]
    char* base = (char*)d_ws;
    size_t off = 65536;
    int* cnt = (int*)(base + off);                                // [B*NCELL]
    const size_t cnt_bytes = (size_t)B * NCELL * sizeof(int);
    int* ocnt = (int*)(base + off + cnt_bytes);                   // 1 int
    size_t boff = (off + cnt_bytes + 256) & ~(size_t)255;
    float4* buckets = (float4*)(base + boff);                     // [B*NCELL*CAP]
    const size_t bkt_bytes = (size_t)B * NCELL * CAP * sizeof(float4);
    float4* ovf = (float4*)(base + boff + bkt_bytes);             // [B*V] worst case
    const size_t need = boff + bkt_bytes + (size_t)total * sizeof(float4);

    if (ws_size >= need) {
        // zero cell counts + overflow counter (one small fill)
        hipMemsetAsync(cnt, 0, cnt_bytes + 64, stream);
        bin_kernel<<<(total + 255) / 256, 256, 0, stream>>>(
            obj, cnt, ocnt, buckets, ovf, total, V);
        const int qthreads = B * NH * SPLIT;
        query_kernel<<<(qthreads + 255) / 256, 256, 0, stream>>>(
            hand, cnt, buckets, ovf, ocnt, dist, B);
    } else {
        // brute-force fallback (uint bit-pattern mins == float d2)
        hipMemsetAsync(d_ws, 0x7F, (size_t)B * NH * sizeof(unsigned int), stream);
        dim3 grid(FNBX, (V + FCHUNK - 1) / FCHUNK, B);
        nn_brute_kernel<<<grid, FBLK, 0, stream>>>(hand, obj,
                                                   (unsigned int*)d_ws, V);
    }
    finalize_kernel<<<1, 256, 0, stream>>>(dist, (float*)d_out, B);
}

// Round 12
// 99.522 us; speedup vs baseline: 1.3069x; 1.3069x over previous
//
#include <hip/hip_runtime.h>
#include <math.h>

// Problem constants
constexpr int NH    = 778;           // hand verts per batch
constexpr int GRIDC = 16;            // cells per axis (0.1 m cube -> 6.25 mm cells)
constexpr int NCELL = GRIDC * GRIDC * GRIDC;   // 4096
constexpr int CAP   = 40;            // bucket cap (Poisson mean ~9.8; P(>40)~1e-14)
constexpr float CELL     = 0.1f / GRIDC;       // 0.00625
constexpr float INV_CELL = GRIDC / 0.1f;       // 160

__device__ __forceinline__ int clampc(int v) {
    return min(GRIDC - 1, max(0, v));
}

// ---------------------------------------------------------------------------
// K1: bin obj points into per-(batch,cell) buckets. Overflow (idx >= CAP)
// goes to a global list tagged with batch (capacity = ALL points -> always
// exact for any distribution). Insertion order is atomic-nondeterministic;
// min over the union is order-independent.
// ---------------------------------------------------------------------------
__global__ __launch_bounds__(256) void bin_kernel(
    const float* __restrict__ obj,   // [B, V, 3] flat
    int* __restrict__ cnt,           // [B*NCELL]
    int* __restrict__ ocnt,          // overflow counter
    float4* __restrict__ buckets,    // [B*NCELL*CAP]
    float4* __restrict__ ovf,        // [B*V] worst case
    int total, int V)
{
    const int i = blockIdx.x * 256 + threadIdx.x;
    if (i >= total) return;
    const float x = obj[3 * i + 0];
    const float y = obj[3 * i + 1];
    const float z = obj[3 * i + 2];
    const int cx = clampc((int)(x * INV_CELL));
    const int cy = clampc((int)(y * INV_CELL));
    const int cz = clampc((int)(z * INV_CELL));
    const int b = i / V;
    const int cell = b * NCELL + (cz * GRIDC + cy) * GRIDC + cx;
    const int idx = atomicAdd(&cnt[cell], 1);
    if (idx < CAP) {
        buckets[(size_t)cell * CAP + idx] = make_float4(x, y, z, 0.f);
    } else {
        const int oi = atomicAdd(ocnt, 1);   // oi < total always
        ovf[oi] = make_float4(x, y, z, __int_as_float(b));
    }
}

// ---------------------------------------------------------------------------
// K2: exact grid NN query — ONE WAVE PER QUERY (R11 post-mortem: SPLIT=4 gave
// 97 blocks total -> latency-bound serial cell walk; now 1556 blocks, the
// radius-1 cube is scanned by 54 parallel lanes, dependent-load depth ~2).
// Exactness: h lies inside its own cell, so after completing cube radius r-1
// every unscanned point is >= (r-1)*CELL away; stop iff best <= ((r-1)*CELL)^2.
// Radius-1 cube suffices for ~all queries (E[NN] ~1.6mm << 6.25mm cell).
// ---------------------------------------------------------------------------
__global__ __launch_bounds__(256) void query_kernel(
    const float* __restrict__ hand,    // [B, NH, 3] flat
    const int* __restrict__ cnt,       // [B*NCELL]
    const float4* __restrict__ buckets,// [B*NCELL*CAP]
    const float4* __restrict__ ovf,
    const int* __restrict__ ocnt,
    float* __restrict__ dist,          // [B*NH] min d2
    int B)
{
    const int gid  = blockIdx.x * 256 + threadIdx.x;
    const int i    = gid >> 6;          // query (hand point) id: 1 wave each
    const int lane = gid & 63;
    if (i >= B * NH) return;
    const int b = i / NH;

    const float hx = hand[3 * i + 0];
    const float hy = hand[3 * i + 1];
    const float hz = hand[3 * i + 2];
    const int hcx = clampc((int)(hx * INV_CELL));
    const int hcy = clampc((int)(hy * INV_CELL));
    const int hcz = clampc((int)(hz * INV_CELL));
    const int cbase = b * NCELL;

    float best = 3.4e38f;

    // phase 1: radius-1 cube (27 cells), 2 lanes per cell (lanes 0..53)
    if (lane < 54) {
        const int cl  = lane >> 1;
        const int sub = lane & 1;
        const int cx = hcx + (cl % 3) - 1;
        const int cy = hcy + ((cl / 3) % 3) - 1;
        const int cz = hcz + (cl / 9) - 1;
        if (cx >= 0 && cx < GRIDC && cy >= 0 && cy < GRIDC &&
            cz >= 0 && cz < GRIDC) {
            const int cell = cbase + (cz * GRIDC + cy) * GRIDC + cx;
            const int n = min(cnt[cell], CAP);
            const float4* bp = buckets + (size_t)cell * CAP;
            for (int k = sub; k < n; k += 2) {   // independent 16B loads
                const float4 p = bp[k];
                const float dx = p.x - hx, dy = p.y - hy, dz = p.z - hz;
                best = fminf(best, fmaf(dx, dx, fmaf(dy, dy, dz * dz)));
            }
        }
    }

    // overflow list (normally empty), lane-strided
    const int on = *ocnt;
    for (int k = lane; k < on; k += 64) {
        const float4 p = ovf[k];
        if (__float_as_int(p.w) == b) {
            const float dx = p.x - hx, dy = p.y - hy, dz = p.z - hz;
            best = fminf(best, fmaf(dx, dx, fmaf(dy, dy, dz * dz)));
        }
    }

#pragma unroll
    for (int d = 1; d < 64; d <<= 1) best = fminf(best, __shfl_xor(best, d));

    // rare path: expanding shells, lane-strided over shell cells
    for (int r = 2; r < GRIDC; ++r) {
        const float bnd = (float)(r - 1) * CELL;
        if (best <= bnd * bnd) break;
        const int side = 2 * r + 1;
        const int ncells = side * side * side;
        for (int ci = lane; ci < ncells; ci += 64) {
            const int dx = ci % side - r;
            const int dy = (ci / side) % side - r;
            const int dz = ci / (side * side) - r;
            if (max(max(abs(dx), abs(dy)), abs(dz)) != r) continue; // shell only
            const int cx = hcx + dx, cy = hcy + dy, cz = hcz + dz;
            if (cx < 0 || cx >= GRIDC || cy < 0 || cy >= GRIDC ||
                cz < 0 || cz >= GRIDC) continue;
            const int cell = cbase + (cz * GRIDC + cy) * GRIDC + cx;
            const int n = min(cnt[cell], CAP);
            const float4* bp = buckets + (size_t)cell * CAP;
            for (int k = 0; k < n; ++k) {
                const float4 p = bp[k];
                const float ddx = p.x - hx, ddy = p.y - hy, ddz = p.z - hz;
                best = fminf(best, fmaf(ddx, ddx, fmaf(ddy, ddy, ddz * ddz)));
            }
        }
#pragma unroll
        for (int d = 1; d < 64; d <<= 1) best = fminf(best, __shfl_xor(best, d));
    }

    if (lane == 0) dist[i] = best;
}

// ---------------------------------------------------------------------------
// Fallback brute-force (R10 kernel) if ws is too small for the grid. Writes
// uint bit-pattern mins of d2 — identical representation to plain float d2.
// ---------------------------------------------------------------------------
typedef float v2f __attribute__((ext_vector_type(2)));
constexpr int FT = 16, FG = 4, FBLK = 256, FCHUNK = 2560;
constexpr int FNBX = (NH + FG * FT - 1) / (FG * FT);
constexpr int FLPP = FCHUNK / FBLK, FPP = FLPP / 2;

__global__ __launch_bounds__(FBLK, 2) void nn_brute_kernel(
    const float* __restrict__ hand, const float* __restrict__ obj,
    unsigned int* __restrict__ minb, int V)
{
    __shared__ float s_red[4][16 * 65];
    const int bx = blockIdx.x, c = blockIdx.y, b = blockIdx.z;
    const int tid = threadIdx.x, wave = tid >> 6, lane = tid & 63;
    const int r = lane & 15, seg = lane >> 4;
    const float* ob = obj + (size_t)b * V * 3;
    const int base = c * FCHUNK + tid;
    v2f ox2[FPP], oy2[FPP], oz2[FPP], oq2[FPP];
#pragma unroll
    for (int p = 0; p < FPP; ++p) {
        const int ja = min(base + (2 * p + 0) * FBLK, V - 1);
        const int jb = min(base + (2 * p + 1) * FBLK, V - 1);
        const float xa = ob[3 * ja], ya = ob[3 * ja + 1], za = ob[3 * ja + 2];
        const float xb = ob[3 * jb], yb = ob[3 * jb + 1], zb = ob[3 * jb + 2];
        ox2[p] = (v2f){-2.f * xa, -2.f * xb};
        oy2[p] = (v2f){-2.f * ya, -2.f * yb};
        oz2[p] = (v2f){-2.f * za, -2.f * zb};
        oq2[p] = (v2f){fmaf(xa, xa, fmaf(ya, ya, za * za)),
                       fmaf(xb, xb, fmaf(yb, yb, zb * zb))};
    }
    const float* hb = hand + (size_t)b * NH * 3;
    float* sw = &s_red[wave][0];
#pragma unroll 1
    for (int g = 0; g < FG; ++g) {
        float hx[FT], hy[FT], hz[FT], m[FT];
#pragma unroll
        for (int t = 0; t < FT; ++t) {
            const int h = min((bx * FG + g) * FT + t, NH - 1);
            hx[t] = hb[3 * h]; hy[t] = hb[3 * h + 1]; hz[t] = hb[3 * h + 2];
            m[t] = 3.4e38f;
        }
#pragma unroll
        for (int p = 0; p < FPP; ++p) {
#pragma unroll
            for (int t = 0; t < FT; ++t) {
                v2f a = __builtin_elementwise_fma(ox2[p], (v2f){hx[t], hx[t]}, oq2[p]);
                a = __builtin_elementwise_fma(oy2[p], (v2f){hy[t], hy[t]}, a);
                a = __builtin_elementwise_fma(oz2[p], (v2f){hz[t], hz[t]}, a);
                m[t] = fminf(fminf(a.x, a.y), m[t]);
            }
        }
#pragma unroll
        for (int t = 0; t < FT; ++t) {
            const float hq = fmaf(hx[t], hx[t], fmaf(hy[t], hy[t], hz[t] * hz[t]));
            sw[t * 65 + lane] = m[t] + hq;
        }
        __builtin_amdgcn_wave_barrier();
        float v = 3.4e38f;
        const int rb = r * 65 + seg * 16;
#pragma unroll
        for (int j = 0; j < 16; ++j) v = fminf(v, sw[rb + j]);
        __builtin_amdgcn_wave_barrier();
        v = fminf(v, __shfl_xor(v, 16));
        v = fminf(v, __shfl_xor(v, 32));
        if (seg == 0) {
            const int hidx = (bx * FG + g) * FT + r;
            if (hidx < NH) {
                const unsigned bits = __float_as_uint(fmaxf(v, 0.f));
                unsigned int* p = &minb[b * NH + hidx];
                if (bits < *((volatile unsigned int*)p)) atomicMin(p, bits);
            }
        }
    }
}

// ---------------------------------------------------------------------------
// Final reduction -> 6 scalar outputs (dist buffer holds d2 as plain floats)
// ---------------------------------------------------------------------------
__global__ __launch_bounds__(256) void finalize_kernel(
    const float* __restrict__ dist, float* __restrict__ out, int B)
{
    constexpr float COLL = 0.005f;
    constexpr float CONT = 0.01f;
    const int total = B * NH;
    const int tid = threadIdx.x;

    double sum_d = 0.0, pen_sum = 0.0, att_sum = 0.0;
    int pen_cnt = 0, att_cnt = 0;
    for (int i = tid; i < total; i += 256) {
        const float d = sqrtf(fmaxf(dist[i], 0.f));
        sum_d += (double)d;
        if (d < COLL) { const float t = COLL - d; pen_sum += (double)(t * t); pen_cnt++; }
        const int n = i % NH;
        const bool isc = (n == 745) | (n == 317) | (n == 444) | (n == 556) |
                         (n == 673) | (n == 95)  | (n == 182) | (n == 234) |
                         (n == 279) | (n == 320);
        if (isc & (d > COLL) & (d < CONT)) { att_sum += (double)(d * d); att_cnt++; }
    }

    __shared__ double sd[256], sp[256], sa[256];
    __shared__ int    cp[256], ca[256];
    sd[tid] = sum_d; sp[tid] = pen_sum; sa[tid] = att_sum;
    cp[tid] = pen_cnt; ca[tid] = att_cnt;
    __syncthreads();
    for (int off = 128; off > 0; off >>= 1) {
        if (tid < off) {
            sd[tid] += sd[tid + off]; sp[tid] += sp[tid + off];
            sa[tid] += sa[tid + off];
            cp[tid] += cp[tid + off]; ca[tid] += ca[tid + off];
        }
        __syncthreads();
    }
    if (tid == 0) {
        const double pen_loss = cp[0] > 0 ? sp[0] / (double)cp[0] : 0.0;
        const double att_loss = ca[0] > 0 ? sa[0] / (double)ca[0] : 0.0;
        out[0] = (float)(100.0 * pen_loss + 10.0 * att_loss);
        out[1] = (float)pen_loss;
        out[2] = (float)att_loss;
        out[3] = (float)(sd[0] / (double)total);
        out[4] = (float)ca[0];
        out[5] = (float)cp[0];
    }
}

extern "C" void kernel_launch(void* const* d_in, const int* in_sizes, int n_in,
                              void* d_out, int out_size, void* d_ws, size_t ws_size,
                              hipStream_t stream) {
    const float* hand = (const float*)d_in[0];  // [B, 778, 3] fp32
    const float* obj  = (const float*)d_in[1];  // [B, V, 3]   fp32
    // d_in[2]/d_in[3] (faces): unused by the loss

    const int B = in_sizes[0] / (NH * 3);
    const int V = in_sizes[1] / (B * 3);
    const int total = B * V;

    // workspace layout
    float* dist = (float*)d_ws;                                   // [B*NH]
    char* base = (char*)d_ws;
    size_t off = 65536;
    int* cnt = (int*)(base + off);                                // [B*NCELL]
    const size_t cnt_bytes = (size_t)B * NCELL * sizeof(int);
    int* ocnt = (int*)(base + off + cnt_bytes);                   // 1 int
    size_t boff = (off + cnt_bytes + 256) & ~(size_t)255;
    float4* buckets = (float4*)(base + boff);                     // [B*NCELL*CAP]
    const size_t bkt_bytes = (size_t)B * NCELL * CAP * sizeof(float4);
    float4* ovf = (float4*)(base + boff + bkt_bytes);             // [B*V] worst case
    const size_t need = boff + bkt_bytes + (size_t)total * sizeof(float4);

    if (ws_size >= need) {
        // zero cell counts + overflow counter (one small fill)
        hipMemsetAsync(cnt, 0, cnt_bytes + 64, stream);
        bin_kernel<<<(total + 255) / 256, 256, 0, stream>>>(
            obj, cnt, ocnt, buckets, ovf, total, V);
        const int qthreads = B * NH * 64;   // one wave per query
        query_kernel<<<(qthreads + 255) / 256, 256, 0, stream>>>(
            hand, cnt, buckets, ovf, ocnt, dist, B);
    } else {
        // brute-force fallback (uint bit-pattern mins == float d2)
        hipMemsetAsync(d_ws, 0x7F, (size_t)B * NH * sizeof(unsigned int), stream);
        dim3 grid(FNBX, (V + FCHUNK - 1) / FCHUNK, B);
        nn_brute_kernel<<<grid, FBLK, 0, stream>>>(hand, obj,
                                                   (unsigned int*)d_ws, V);
    }
    finalize_kernel<<<1, 256, 0, stream>>>(dist, (float*)d_out, B);
}